// Round 9
// baseline (138.811 us; speedup 1.0000x reference)
//
#include <hip/hip_runtime.h>
#include <hip/hip_cooperative_groups.h>
#include <hip/hip_bf16.h>
#include <math.h>

namespace cg = cooperative_groups;

#define Nn 1536
#define Bb 2
#define Hh 32
#define Ll 16
#define Nb 96          // Nn/16
#define TREG 4656      // Nb*(Nb+1)/2 regions per batch
#define KSTEPS 48      // 1536/32

typedef short bf16x8 __attribute__((ext_vector_type(8)));
typedef _Float16 f16x8 __attribute__((ext_vector_type(8)));
typedef float f32x4 __attribute__((ext_vector_type(4)));
typedef short short4v __attribute__((ext_vector_type(4)));

__device__ __forceinline__ short f2bf(float x) {
    __hip_bfloat16 h = __float2bfloat16(x);
    return *reinterpret_cast<short*>(&h);
}

// VALU half-swaps (gfx950). Result valid in the LOWER half of each swap domain.
__device__ __forceinline__ float permswap32(float v) {
    float a = v, b = v;
    asm("v_permlane32_swap_b32 %0, %1" : "+v"(a), "+v"(b));
    return a;
}
__device__ __forceinline__ float permswap16(float v) {
    float a = v, b = v;
    asm("v_permlane16_swap_b32 %0, %1" : "+v"(a), "+v"(b));
    return a;
}

// ================= fused GCN: prep + 3 MFMA prop layers + heads, one cooperative kernel =================
// grid = Bb*Nb blocks (one per 16-row M-tile), 256 threads. A-tile lives in LDS for all 3 layers.
__global__ __launch_bounds__(256, 1) void gcn_kernel(
    const float* __restrict__ A, const float* __restrict__ emb,
    const float* __restrict__ W1, const float* __restrict__ b1,
    const float* __restrict__ W2, const float* __restrict__ b2,
    const float* __restrict__ W3, const float* __restrict__ b3,
    const float* __restrict__ Wmu, const float* __restrict__ bmu,
    const float* __restrict__ Wlv, const float* __restrict__ blv,
    const float* __restrict__ E1, const float* __restrict__ e1,
    __hip_bfloat16* __restrict__ xsTa, __hip_bfloat16* __restrict__ xsTb,
    float* __restrict__ mu, float* __restrict__ lv,
    _Float16* __restrict__ Uh, _Float16* __restrict__ Vh) {
    __shared__ short sA[16][1544];      // 49.4 KB bf16 A_hat tile (pad 8 shorts: uniform banks)
    __shared__ float sRed[4][64][8];    // 8 KB k-split reduce
    __shared__ float sH[16][33];        // current layer h (residual source)
    __shared__ float sWt[32][32];       // staged next-layer weight
    __shared__ float sMu[16][16];
    __shared__ float sdinv[16];

    cg::grid_group grid = cg::this_grid();
    int t = threadIdx.x, lane = t & 63, w = t >> 6;
    int x = lane & 15, g = lane >> 4;
    int mt = blockIdx.x;
    int b = mt / Nb, it = mt - b * Nb;
    int i0 = it * 16;

    // ---- phase 0: own A rows -> LDS bf16 tile (+self-loop fill), dinv, layer-1 xsT ----
#pragma unroll 1
    for (int rr = 0; rr < 4; ++rr) {
        int r = w * 4 + rr;
        int i = i0 + r;
        const float* Arow = A + ((size_t)b * Nn + i) * Nn;
        float s = 0.f;
#pragma unroll
        for (int itr = 0; itr < 6; ++itr) {
            int j = itr * 256 + lane * 4;
            float4 a4 = *reinterpret_cast<const float4*>(Arow + j);
            s += a4.x + a4.y + a4.z + a4.w;
            float v0 = (j + 0 == i) ? ((a4.x == 0.f) ? 1.f : a4.x) : a4.x;
            float v1 = (j + 1 == i) ? ((a4.y == 0.f) ? 1.f : a4.y) : a4.y;
            float v2 = (j + 2 == i) ? ((a4.z == 0.f) ? 1.f : a4.z) : a4.z;
            float v3 = (j + 3 == i) ? ((a4.w == 0.f) ? 1.f : a4.w) : a4.w;
            short4v sv = { f2bf(v0), f2bf(v1), f2bf(v2), f2bf(v3) };
            *reinterpret_cast<short4v*>(&sA[r][j]) = sv;
        }
#pragma unroll
        for (int o = 1; o < 64; o <<= 1) s += __shfl_xor(s, o, 64);
        float d = Arow[i];
        float fill = (d == 0.f) ? 1.f : d;
        float deg = s - d + fill;
        if (lane == 0) sdinv[r] = (deg > 0.f) ? (1.f / sqrtf(deg)) : 0.f;
    }
    __syncthreads();
    {   // layer-1 xsT for own rows: threads grouped so 16 consecutive rows/channel pack
        int r = t & 15, c = (t >> 4) * 2;
        int i = i0 + r;
        float di = sdinv[r];
        float acc0 = 0.f, acc1 = 0.f;
#pragma unroll
        for (int m = 0; m < 8; ++m) {
            float ev = emb[(size_t)i * 8 + m];
            acc0 = fmaf(ev, W1[m * Hh + c], acc0);
            acc1 = fmaf(ev, W1[m * Hh + c + 1], acc1);
        }
        ((short*)xsTa)[(size_t)(b * Hh + c) * Nn + i] = f2bf(di * acc0);
        ((short*)xsTa)[(size_t)(b * Hh + c + 1) * Nn + i] = f2bf(di * acc1);
    }
    grid.sync();

    // ---- phases 1..3: prop layers ----
    const __hip_bfloat16* xsCur = xsTa;
    __hip_bfloat16* xsNext = xsTb;
#pragma unroll 1
    for (int layer = 0; layer < 3; ++layer) {
        const float* bias = (layer == 0) ? b1 : (layer == 1) ? b2 : b3;
        const float* Wnext = (layer == 0) ? W2 : (layer == 1) ? W3 : nullptr;
        if (Wnext) {
            for (int k = t; k < 1024; k += 256) sWt[k >> 5][k & 31] = Wnext[k];
        }

        const short* X0 = (const short*)xsCur + ((size_t)(b * Hh) + x) * Nn + 8 * g;
        const short* X1 = X0 + (size_t)16 * Nn;
        f32x4 acc0 = {0.f, 0.f, 0.f, 0.f};
        f32x4 acc1 = {0.f, 0.f, 0.f, 0.f};
        int ks0 = w * (KSTEPS / 4);
#pragma unroll
        for (int ks = ks0; ks < ks0 + KSTEPS / 4; ++ks) {
            bf16x8 af = *reinterpret_cast<const bf16x8*>(&sA[x][ks * 32 + 8 * g]);
            bf16x8 bb0 = *reinterpret_cast<const bf16x8*>(X0 + ks * 32);
            bf16x8 bb1 = *reinterpret_cast<const bf16x8*>(X1 + ks * 32);
            acc0 = __builtin_amdgcn_mfma_f32_16x16x32_bf16(af, bb0, acc0, 0, 0, 0);
            acc1 = __builtin_amdgcn_mfma_f32_16x16x32_bf16(af, bb1, acc1, 0, 0, 0);
        }
#pragma unroll
        for (int r = 0; r < 4; ++r) { sRed[w][lane][r] = acc0[r]; sRed[w][lane][4 + r] = acc1[r]; }
        __syncthreads();
        {
            int xx = lane & 15, gg = lane >> 4;
#pragma unroll
            for (int q = 0; q < 2; ++q) {
                int ri = w * 2 + q;
                float v = sRed[0][lane][ri] + sRed[1][lane][ri] + sRed[2][lane][ri] + sRed[3][lane][ri];
                int row = 4 * gg + (ri & 3);
                int c = (ri < 4) ? xx : (16 + xx);
                v = sdinv[row] * v + bias[c];
                v = fmaxf(v, 0.f);
                if (layer > 0) v += sH[row][c];   // residual
                sH[row][c] = v;
            }
        }
        __syncthreads();

        if (Wnext) {   // next-layer xsT for own rows
            for (int k = t; k < 512; k += 256) {
                int r = k & 15, c = k >> 4;
                float acc = 0.f;
#pragma unroll
                for (int m = 0; m < 32; ++m) acc = fmaf(sH[r][m], sWt[m][c], acc);
                ((short*)xsNext)[(size_t)(b * Hh + c) * Nn + i0 + r] = f2bf(sdinv[r] * acc);
            }
            const __hip_bfloat16* tmp = xsCur;
            xsCur = xsNext;
            xsNext = (__hip_bfloat16*)tmp;
            grid.sync();
        }
    }

    // ---- heads: mu / logvar, then U/V for the edge MLP ----
    {
        int r = t >> 4, ll = t & 15;
        float am = bmu[ll], av = blv[ll];
#pragma unroll
        for (int m = 0; m < 32; ++m) {
            float hv = sH[r][m];
            am = fmaf(hv, Wmu[m * Ll + ll], am);
            av = fmaf(hv, Wlv[m * Ll + ll], av);
        }
        size_t o = ((size_t)b * Nn + i0 + r) * Ll + ll;
        mu[o] = am; lv[o] = av;
        sMu[r][ll] = am;
    }
    __syncthreads();
#pragma unroll
    for (int q = 0; q < 4; ++q) {
        int idx = q * 256 + t;
        int r = idx >> 6, c = idx & 63;
        float ua = e1[c], va = 0.f;
#pragma unroll
        for (int m = 0; m < Ll; ++m) {
            float zm = sMu[r][m];
            ua = fmaf(zm, E1[m * 64 + c], ua);
            va = fmaf(zm, E1[(16 + m) * 64 + c], va);
        }
        size_t o = ((size_t)b * Nn + i0 + r) * 64 + c;
        Uh[o] = (_Float16)ua;
        Vh[o] = (_Float16)va;
    }
}

// ---------------- edge MLP: one wave per 16x16 region (unchanged from R7) ----------------
__global__ __launch_bounds__(256) void edge_kernel(
    const _Float16* __restrict__ Uh, const _Float16* __restrict__ Vh,
    const float* __restrict__ E2, const float* __restrict__ e2,
    const float* __restrict__ E3, const float* __restrict__ e3,
    float* __restrict__ adj) {
    __shared__ float sW[4][16][20];
    int t = threadIdx.x, lane = t & 63, w = t >> 6;
    int x = lane & 15, g = lane >> 4;

    f16x8 ea[2][2];
#pragma unroll
    for (int ct = 0; ct < 2; ++ct)
#pragma unroll
        for (int ks = 0; ks < 2; ++ks)
#pragma unroll
            for (int jj = 0; jj < 8; ++jj)
                ea[ct][ks][jj] = (_Float16)E2[(32 * ks + 8 * g + jj) * Hh + 16 * ct + x];

    float e2a[4], e2b[4], E3a[4], E3b[4];
#pragma unroll
    for (int rg = 0; rg < 4; ++rg) {
        e2a[rg] = e2[4 * g + rg];      E3a[rg] = E3[4 * g + rg];
        e2b[rg] = e2[16 + 4 * g + rg]; E3b[rg] = E3[16 + 4 * g + rg];
    }
    float e3s = e3[0];

    int tr = blockIdx.x * 4 + w;
    int b = 0;
    if (tr >= TREG) { b = 1; tr -= TREG; }
    float ft = (float)tr;
    int ib = (int)((193.0f - sqrtf(193.0f * 193.0f - 8.0f * ft)) * 0.5f);
    ib = ib < 0 ? 0 : (ib > Nb - 1 ? Nb - 1 : ib);
    while (ib < Nb - 1 && (ib + 1) * Nb - ((ib + 1) * ib) / 2 <= tr) ++ib;
    while (ib > 0 && ib * Nb - (ib * (ib - 1)) / 2 > tr) --ib;
    int jb = ib + (tr - (ib * Nb - (ib * (ib - 1)) / 2));
    int i0 = ib * 16, j0 = jb * 16;
    bool diag = (ib == jb);

    const f16x8* Vrow = reinterpret_cast<const f16x8*>(Vh + ((size_t)b * Nn + j0 + x) * 64);
    f16x8 vf0 = Vrow[g];
    f16x8 vf1 = Vrow[4 + g];

    const f16x8* Ubase = reinterpret_cast<const f16x8*>(Uh + ((size_t)b * Nn + i0) * 64);

    if (diag && lane < 16) sW[w][lane][lane] = 0.f;

    const f16x8 fz = {0, 0, 0, 0, 0, 0, 0, 0};
#pragma unroll 4
    for (int r = 0; r < 16; ++r) {
        f16x8 u0 = Ubase[r * 8 + g];
        f16x8 u1 = Ubase[r * 8 + 4 + g];

        f16x8 af0 = __builtin_elementwise_max(u0 + vf0, fz);
        f16x8 af1 = __builtin_elementwise_max(u1 + vf1, fz);

        f32x4 acc0 = {e2a[0], e2a[1], e2a[2], e2a[3]};
        f32x4 acc1 = {e2b[0], e2b[1], e2b[2], e2b[3]};
        acc0 = __builtin_amdgcn_mfma_f32_16x16x32_f16(ea[0][0], af0, acc0, 0, 0, 0);
        acc0 = __builtin_amdgcn_mfma_f32_16x16x32_f16(ea[0][1], af1, acc0, 0, 0, 0);
        acc1 = __builtin_amdgcn_mfma_f32_16x16x32_f16(ea[1][0], af0, acc1, 0, 0, 0);
        acc1 = __builtin_amdgcn_mfma_f32_16x16x32_f16(ea[1][1], af1, acc1, 0, 0, 0);

        float part = 0.f;
#pragma unroll
        for (int rg = 0; rg < 4; ++rg) {
            part = fmaf(fmaxf(acc0[rg], 0.f), E3a[rg], part);
            part = fmaf(fmaxf(acc1[rg], 0.f), E3b[rg], part);
        }
        part += permswap32(part);
        part += permswap16(part);

        float logit = part + e3s;
        float wv = __builtin_amdgcn_rcpf(1.f + __expf(-logit));

        if (g == 0) {
            if (!diag) {
                adj[((size_t)b * Nn + i0 + r) * Nn + j0 + x] = wv;
                sW[w][x][r] = wv;
            } else if (x > r) {
                sW[w][r][x] = wv;
                sW[w][x][r] = wv;
            }
        }
    }

    {
        int rr = lane >> 2, m4 = (lane & 3) * 4;
        float4 wv4 = *reinterpret_cast<const float4*>(&sW[w][rr][m4]);
        if (!diag)
            *reinterpret_cast<float4*>(&adj[((size_t)b * Nn + j0 + rr) * Nn + i0 + m4]) = wv4;
        else
            *reinterpret_cast<float4*>(&adj[((size_t)b * Nn + i0 + rr) * Nn + i0 + m4]) = wv4;
    }
}

extern "C" void kernel_launch(void* const* d_in, const int* in_sizes, int n_in,
                              void* d_out, int out_size, void* d_ws, size_t ws_size,
                              hipStream_t stream) {
    const float* A   = (const float*)d_in[0];
    const float* emb = (const float*)d_in[1];
    const float* W1  = (const float*)d_in[2];  const float* b1  = (const float*)d_in[3];
    const float* W2  = (const float*)d_in[4];  const float* b2  = (const float*)d_in[5];
    const float* W3  = (const float*)d_in[6];  const float* b3  = (const float*)d_in[7];
    const float* Wmu = (const float*)d_in[8];  const float* bmu = (const float*)d_in[9];
    const float* Wlv = (const float*)d_in[10]; const float* blv = (const float*)d_in[11];
    const float* E1  = (const float*)d_in[12]; const float* e1  = (const float*)d_in[13];
    const float* E2  = (const float*)d_in[14]; const float* e2  = (const float*)d_in[15];
    const float* E3  = (const float*)d_in[16]; const float* e3  = (const float*)d_in[17];

    float* out = (float*)d_out;
    float* ws  = (float*)d_ws;
    // ws layout (f32 slots): xsTa[49152] xsTb[49152] Uh[98304] Vh[98304]
    __hip_bfloat16* xsTa = (__hip_bfloat16*)(ws);
    __hip_bfloat16* xsTb = (__hip_bfloat16*)(ws + 49152);
    _Float16* Uh = (_Float16*)(ws + 98304);
    _Float16* Vh = (_Float16*)(ws + 196608);

    float* mu_out = out + (size_t)Bb * Nn * Nn;
    float* lv_out = mu_out + (size_t)Bb * Nn * Ll;

    void* args[] = {
        (void*)&A, (void*)&emb,
        (void*)&W1, (void*)&b1, (void*)&W2, (void*)&b2, (void*)&W3, (void*)&b3,
        (void*)&Wmu, (void*)&bmu, (void*)&Wlv, (void*)&blv,
        (void*)&E1, (void*)&e1,
        (void*)&xsTa, (void*)&xsTb,
        (void*)&mu_out, (void*)&lv_out, (void*)&Uh, (void*)&Vh
    };
    hipLaunchCooperativeKernel((void*)gcn_kernel, dim3(Bb * Nb), dim3(256),
                               args, 0, stream);

    edge_kernel<<<(2 * TREG + 3) / 4, 256, 0, stream>>>(Uh, Vh, E2, e2, E3, e3, out);
}

// Round 10
// 99.274 us; speedup vs baseline: 1.3983x; 1.3983x over previous
//
#include <hip/hip_runtime.h>
#include <hip/hip_bf16.h>
#include <math.h>

#define Nn 1536
#define Bb 2
#define Hh 32
#define Ll 16
#define Nb 96          // Nn/16
#define TREG 4656      // Nb*(Nb+1)/2 regions per batch
#define KSTEPS 48      // 1536/32

typedef short bf16x8 __attribute__((ext_vector_type(8)));
typedef _Float16 f16x8 __attribute__((ext_vector_type(8)));
typedef float f32x4 __attribute__((ext_vector_type(4)));
typedef short short4v __attribute__((ext_vector_type(4)));

__device__ __forceinline__ short f2bf(float x) {
    __hip_bfloat16 h = __float2bfloat16(x);
    return *reinterpret_cast<short*>(&h);
}

// VALU half-swaps (gfx950). Result valid in the LOWER half of each swap domain.
__device__ __forceinline__ float permswap32(float v) {
    float a = v, b = v;
    asm("v_permlane32_swap_b32 %0, %1" : "+v"(a), "+v"(b));
    return a;
}
__device__ __forceinline__ float permswap16(float v) {
    float a = v, b = v;
    asm("v_permlane16_swap_b32 %0, %1" : "+v"(a), "+v"(b));
    return a;
}

// ---------------- prep: rowsum -> dinv, A -> bf16 with self-loop fill, fused layer-1 xsT ----------------
__global__ void prep_kernel(const float* __restrict__ A,
                            __hip_bfloat16* __restrict__ Abf,
                            float* __restrict__ dinv,
                            const float* __restrict__ emb,
                            const float* __restrict__ W1,
                            __hip_bfloat16* __restrict__ xsT) {
    int w = threadIdx.x >> 6;
    int lane = threadIdx.x & 63;
    int bi = blockIdx.x * 4 + w;
    if (bi >= Bb * Nn) return;
    int b = (bi >= Nn) ? 1 : 0;
    int i = bi - b * Nn;
    const float* Arow = A + (size_t)bi * Nn;
    short* Brow = (short*)Abf + (size_t)bi * Nn;
    float s = 0.f;
#pragma unroll
    for (int it = 0; it < 6; ++it) {
        int j = it * 256 + lane * 4;
        float4 a4 = *reinterpret_cast<const float4*>(Arow + j);
        s += a4.x + a4.y + a4.z + a4.w;
        float e0 = (j + 0 == i) ? ((a4.x == 0.f) ? 1.f : a4.x) : a4.x;
        float e1 = (j + 1 == i) ? ((a4.y == 0.f) ? 1.f : a4.y) : a4.y;
        float e2v = (j + 2 == i) ? ((a4.z == 0.f) ? 1.f : a4.z) : a4.z;
        float e3v = (j + 3 == i) ? ((a4.w == 0.f) ? 1.f : a4.w) : a4.w;
        short4v sv = { f2bf(e0), f2bf(e1), f2bf(e2v), f2bf(e3v) };
        *reinterpret_cast<short4v*>(Brow + j) = sv;
    }
#pragma unroll
    for (int o = 1; o < 64; o <<= 1) s += __shfl_xor(s, o, 64);
    float d = Arow[i];
    float fill = (d == 0.f) ? 1.f : d;
    float deg = s - d + fill;
    float di = (deg > 0.f) ? (1.f / sqrtf(deg)) : 0.f;
    if (lane == 0) dinv[bi] = di;
    if (lane < 32) {
        float acc = 0.f;
#pragma unroll
        for (int m = 0; m < 8; ++m)
            acc = fmaf(emb[(size_t)i * 8 + m], W1[m * Hh + lane], acc);
        ((short*)xsT)[(size_t)(b * Hh + lane) * Nn + i] = f2bf(di * acc);
    }
}

// ---------------- GCN propagation via MFMA + fused epilogues ----------------
__global__ __launch_bounds__(256, 1) void prop_kernel(
    const __hip_bfloat16* __restrict__ Abf, const __hip_bfloat16* __restrict__ xsT,
    const float* __restrict__ dinv, const float* __restrict__ bias,
    const float* __restrict__ res, float* __restrict__ out, int has_res,
    const float* __restrict__ Wn, __hip_bfloat16* __restrict__ xsT_next,
    int final_stage,
    const float* __restrict__ Wmu, const float* __restrict__ bmu,
    const float* __restrict__ Wlv, const float* __restrict__ blv,
    const float* __restrict__ E1, const float* __restrict__ e1,
    float* __restrict__ mu, float* __restrict__ lv,
    _Float16* __restrict__ Uh, _Float16* __restrict__ Vh) {
    __shared__ float sRed[4][64][8];
    __shared__ float sOut[16][33];
    __shared__ float sWn[32][32];
    __shared__ float sMu[16][16];
    int t = threadIdx.x, lane = t & 63, w = t >> 6;
    int x = lane & 15, g = lane >> 4;
    int mt = blockIdx.x;
    int b = mt / Nb, it = mt - b * Nb;
    int i0 = it * 16;

    if (Wn) {
        for (int k = t; k < 1024; k += 256) sWn[k >> 5][k & 31] = Wn[k];
    }

    const short* Arow = (const short*)Abf + ((size_t)b * Nn + i0 + x) * Nn + 8 * g;
    const short* X0 = (const short*)xsT + ((size_t)(b * Hh) + x) * Nn + 8 * g;
    const short* X1 = X0 + (size_t)16 * Nn;

    f32x4 acc0 = {0.f, 0.f, 0.f, 0.f};
    f32x4 acc1 = {0.f, 0.f, 0.f, 0.f};
    int ks0 = w * (KSTEPS / 4);
#pragma unroll
    for (int ks = ks0; ks < ks0 + KSTEPS / 4; ++ks) {
        bf16x8 af = *reinterpret_cast<const bf16x8*>(Arow + ks * 32);
        bf16x8 b0 = *reinterpret_cast<const bf16x8*>(X0 + ks * 32);
        bf16x8 b1 = *reinterpret_cast<const bf16x8*>(X1 + ks * 32);
        acc0 = __builtin_amdgcn_mfma_f32_16x16x32_bf16(af, b0, acc0, 0, 0, 0);
        acc1 = __builtin_amdgcn_mfma_f32_16x16x32_bf16(af, b1, acc1, 0, 0, 0);
    }
#pragma unroll
    for (int r = 0; r < 4; ++r) { sRed[w][lane][r] = acc0[r]; sRed[w][lane][4 + r] = acc1[r]; }
    __syncthreads();

    int xx = lane & 15, gg = lane >> 4;
#pragma unroll
    for (int q = 0; q < 2; ++q) {
        int ri = w * 2 + q;
        float v = sRed[0][lane][ri] + sRed[1][lane][ri] + sRed[2][lane][ri] + sRed[3][lane][ri];
        int row = 4 * gg + (ri & 3);
        int c = (ri < 4) ? xx : (16 + xx);
        int bi = b * Nn + i0 + row;
        v = dinv[bi] * v + bias[c];
        v = fmaxf(v, 0.f);
        if (has_res) v += res[(size_t)bi * Hh + c];
        out[(size_t)bi * Hh + c] = v;
        sOut[row][c] = v;
    }
    __syncthreads();

    if (Wn) {
        for (int k = t; k < 512; k += 256) {
            int r = k >> 5, c = k & 31;
            float acc = 0.f;
#pragma unroll
            for (int m = 0; m < 32; ++m) acc = fmaf(sOut[r][m], sWn[m][c], acc);
            int bi = b * Nn + i0 + r;
            ((short*)xsT_next)[(size_t)(b * Hh + c) * Nn + i0 + r] = f2bf(dinv[bi] * acc);
        }
    }
    if (final_stage) {
        {
            int r = t >> 4, ll = t & 15;
            float am = bmu[ll], av = blv[ll];
#pragma unroll
            for (int m = 0; m < 32; ++m) {
                float hv = sOut[r][m];
                am = fmaf(hv, Wmu[m * Ll + ll], am);
                av = fmaf(hv, Wlv[m * Ll + ll], av);
            }
            size_t o = ((size_t)b * Nn + i0 + r) * Ll + ll;
            mu[o] = am; lv[o] = av;
            sMu[r][ll] = am;
        }
        __syncthreads();
#pragma unroll
        for (int q = 0; q < 4; ++q) {
            int idx = q * 256 + t;
            int r = idx >> 6, c = idx & 63;
            float ua = e1[c], va = 0.f;
#pragma unroll
            for (int m = 0; m < Ll; ++m) {
                float zm = sMu[r][m];
                ua = fmaf(zm, E1[m * 64 + c], ua);
                va = fmaf(zm, E1[(16 + m) * 64 + c], va);
            }
            size_t o = ((size_t)b * Nn + i0 + r) * 64 + c;
            Uh[o] = (_Float16)ua;
            Vh[o] = (_Float16)va;
        }
    }
}

// ---------------- edge MLP: one wave per region, DEFERRED TAIL (MFMA loop is pure dataflow) ----------------
__global__ __launch_bounds__(256) void edge_kernel(
    const _Float16* __restrict__ Uh, const _Float16* __restrict__ Vh,
    const float* __restrict__ E2, const float* __restrict__ e2,
    const float* __restrict__ E3, const float* __restrict__ e3,
    float* __restrict__ adj) {
    __shared__ float sW[4][16][20];
    int t = threadIdx.x, lane = t & 63, w = t >> 6;
    int x = lane & 15, g = lane >> 4;

    f16x8 ea[2][2];
#pragma unroll
    for (int ct = 0; ct < 2; ++ct)
#pragma unroll
        for (int ks = 0; ks < 2; ++ks)
#pragma unroll
            for (int jj = 0; jj < 8; ++jj)
                ea[ct][ks][jj] = (_Float16)E2[(32 * ks + 8 * g + jj) * Hh + 16 * ct + x];

    float e2a[4], e2b[4], E3a[4], E3b[4];
#pragma unroll
    for (int rg = 0; rg < 4; ++rg) {
        e2a[rg] = e2[4 * g + rg];      E3a[rg] = E3[4 * g + rg];
        e2b[rg] = e2[16 + 4 * g + rg]; E3b[rg] = E3[16 + 4 * g + rg];
    }
    float e3s = e3[0];

    int tr = blockIdx.x * 4 + w;
    int b = 0;
    if (tr >= TREG) { b = 1; tr -= TREG; }
    float ft = (float)tr;
    int ib = (int)((193.0f - sqrtf(193.0f * 193.0f - 8.0f * ft)) * 0.5f);
    ib = ib < 0 ? 0 : (ib > Nb - 1 ? Nb - 1 : ib);
    while (ib < Nb - 1 && (ib + 1) * Nb - ((ib + 1) * ib) / 2 <= tr) ++ib;
    while (ib > 0 && ib * Nb - (ib * (ib - 1)) / 2 > tr) --ib;
    int jb = ib + (tr - (ib * Nb - (ib * (ib - 1)) / 2));
    int i0 = ib * 16, j0 = jb * 16;
    bool diag = (ib == jb);

    const f16x8* Vrow = reinterpret_cast<const f16x8*>(Vh + ((size_t)b * Nn + j0 + x) * 64);
    f16x8 vf0 = Vrow[g];
    f16x8 vf1 = Vrow[4 + g];

    const f16x8* Ubase = reinterpret_cast<const f16x8*>(Uh + ((size_t)b * Nn + i0) * 64);

    if (diag && lane < 16) sW[w][lane][lane] = 0.f;

    const f16x8 fz = {0, 0, 0, 0, 0, 0, 0, 0};

    // phase 1: per-row MFMA + lane-local partial only — rows fully independent,
    // no cross-lane ops, no TRANS ops, no stores -> compiler can pipeline rows.
    float part[16];
#pragma unroll 4
    for (int r = 0; r < 16; ++r) {
        f16x8 u0 = Ubase[r * 8 + g];
        f16x8 u1 = Ubase[r * 8 + 4 + g];
        f16x8 af0 = __builtin_elementwise_max(u0 + vf0, fz);
        f16x8 af1 = __builtin_elementwise_max(u1 + vf1, fz);

        f32x4 acc0 = {e2a[0], e2a[1], e2a[2], e2a[3]};
        f32x4 acc1 = {e2b[0], e2b[1], e2b[2], e2b[3]};
        acc0 = __builtin_amdgcn_mfma_f32_16x16x32_f16(ea[0][0], af0, acc0, 0, 0, 0);
        acc0 = __builtin_amdgcn_mfma_f32_16x16x32_f16(ea[0][1], af1, acc0, 0, 0, 0);
        acc1 = __builtin_amdgcn_mfma_f32_16x16x32_f16(ea[1][0], af0, acc1, 0, 0, 0);
        acc1 = __builtin_amdgcn_mfma_f32_16x16x32_f16(ea[1][1], af1, acc1, 0, 0, 0);

        float p = 0.f;
#pragma unroll
        for (int rg = 0; rg < 4; ++rg) {
            p = fmaf(fmaxf(acc0[rg], 0.f), E3a[rg], p);
            p = fmaf(fmaxf(acc1[rg], 0.f), E3b[rg], p);
        }
        part[r] = p;
    }

    // phase 2: batched cross-lane reduce (16 independent chains -> ILP)
#pragma unroll
    for (int r = 0; r < 16; ++r) part[r] += permswap32(part[r]);
#pragma unroll
    for (int r = 0; r < 16; ++r) part[r] += permswap16(part[r]);

    // phase 3: batched sigmoid (TRANS ops packed back-to-back)
    float wv[16];
#pragma unroll
    for (int r = 0; r < 16; ++r) {
        float logit = part[r] + e3s;
        wv[r] = __builtin_amdgcn_rcpf(1.f + __expf(-logit));
    }

    // phase 4: stores (lanes 0-15 hold valid sums)
    if (g == 0) {
#pragma unroll
        for (int r = 0; r < 16; ++r) {
            if (!diag) {
                adj[((size_t)b * Nn + i0 + r) * Nn + j0 + x] = wv[r];
                sW[w][x][r] = wv[r];
            } else if (x > r) {
                sW[w][r][x] = wv[r];
                sW[w][x][r] = wv[r];
            }
        }
    }

    {
        int rr = lane >> 2, m4 = (lane & 3) * 4;
        float4 wv4 = *reinterpret_cast<const float4*>(&sW[w][rr][m4]);
        if (!diag)
            *reinterpret_cast<float4*>(&adj[((size_t)b * Nn + j0 + rr) * Nn + i0 + m4]) = wv4;
        else
            *reinterpret_cast<float4*>(&adj[((size_t)b * Nn + i0 + rr) * Nn + i0 + m4]) = wv4;
    }
}

extern "C" void kernel_launch(void* const* d_in, const int* in_sizes, int n_in,
                              void* d_out, int out_size, void* d_ws, size_t ws_size,
                              hipStream_t stream) {
    const float* A   = (const float*)d_in[0];
    const float* emb = (const float*)d_in[1];
    const float* W1  = (const float*)d_in[2];  const float* b1  = (const float*)d_in[3];
    const float* W2  = (const float*)d_in[4];  const float* b2  = (const float*)d_in[5];
    const float* W3  = (const float*)d_in[6];  const float* b3  = (const float*)d_in[7];
    const float* Wmu = (const float*)d_in[8];  const float* bmu = (const float*)d_in[9];
    const float* Wlv = (const float*)d_in[10]; const float* blv = (const float*)d_in[11];
    const float* E1  = (const float*)d_in[12]; const float* e1  = (const float*)d_in[13];
    const float* E2  = (const float*)d_in[14]; const float* e2  = (const float*)d_in[15];
    const float* E3  = (const float*)d_in[16]; const float* e3  = (const float*)d_in[17];

    float* out = (float*)d_out;
    float* ws  = (float*)d_ws;
    float* dinv = ws;
    float* hA   = ws + 3072;
    float* hB   = ws + 101376;
    __hip_bfloat16* xsTa = (__hip_bfloat16*)(ws + 199680);
    __hip_bfloat16* xsTb = (__hip_bfloat16*)(ws + 248832);
    _Float16* Uh = (_Float16*)(ws + 297984);
    _Float16* Vh = (_Float16*)(ws + 396288);
    __hip_bfloat16* Abf = (__hip_bfloat16*)out;   // aliases adj region; overwritten by edge later

    float* mu_out = out + (size_t)Bb * Nn * Nn;
    float* lv_out = mu_out + (size_t)Bb * Nn * Ll;

    prep_kernel<<<(Bb * Nn + 3) / 4, 256, 0, stream>>>(A, Abf, dinv, emb, W1, xsTa);

    prop_kernel<<<Bb * Nb, 256, 0, stream>>>(Abf, xsTa, dinv, b1, nullptr, hA, 0,
                                             W2, xsTb, 0,
                                             nullptr, nullptr, nullptr, nullptr,
                                             nullptr, nullptr, nullptr, nullptr,
                                             nullptr, nullptr);
    prop_kernel<<<Bb * Nb, 256, 0, stream>>>(Abf, xsTb, dinv, b2, hA, hB, 1,
                                             W3, xsTa, 0,
                                             nullptr, nullptr, nullptr, nullptr,
                                             nullptr, nullptr, nullptr, nullptr,
                                             nullptr, nullptr);
    prop_kernel<<<Bb * Nb, 256, 0, stream>>>(Abf, xsTa, dinv, b3, hB, hA, 1,
                                             nullptr, nullptr, 1,
                                             Wmu, bmu, Wlv, blv, E1, e1,
                                             mu_out, lv_out, Uh, Vh);

    // Launched TWICE deliberately this round (idempotent): the duration delta vs R7
    // isolates the edge kernel's cost exactly; removed next round.
    edge_kernel<<<(2 * TREG + 3) / 4, 256, 0, stream>>>(Uh, Vh, E2, e2, E3, e3, out);
    edge_kernel<<<(2 * TREG + 3) / 4, 256, 0, stream>>>(Uh, Vh, E2, e2, E3, e3, out);
}

// Round 11
// 76.998 us; speedup vs baseline: 1.8028x; 1.2893x over previous
//
#include <hip/hip_runtime.h>
#include <hip/hip_bf16.h>
#include <math.h>

#define Nn 1536
#define Bb 2
#define Hh 32
#define Ll 16
#define Nb 96          // Nn/16
#define TREG 4656      // Nb*(Nb+1)/2 regions per batch
#define KSTEPS 48      // 1536/32

typedef short bf16x8 __attribute__((ext_vector_type(8)));
typedef _Float16 f16x8 __attribute__((ext_vector_type(8)));
typedef float f32x4 __attribute__((ext_vector_type(4)));
typedef short short4v __attribute__((ext_vector_type(4)));

__device__ __forceinline__ short f2bf(float x) {
    __hip_bfloat16 h = __float2bfloat16(x);
    return *reinterpret_cast<short*>(&h);
}

// VALU half-swaps (gfx950). Result valid in the LOWER half of each swap domain.
__device__ __forceinline__ float permswap32(float v) {
    float a = v, b = v;
    asm("v_permlane32_swap_b32 %0, %1" : "+v"(a), "+v"(b));
    return a;
}
__device__ __forceinline__ float permswap16(float v) {
    float a = v, b = v;
    asm("v_permlane16_swap_b32 %0, %1" : "+v"(a), "+v"(b));
    return a;
}

// ---------------- prep: rowsum -> dinv, A -> bf16 with self-loop fill, fused layer-1 xsT ----------------
__global__ void prep_kernel(const float* __restrict__ A,
                            __hip_bfloat16* __restrict__ Abf,
                            float* __restrict__ dinv,
                            const float* __restrict__ emb,
                            const float* __restrict__ W1,
                            __hip_bfloat16* __restrict__ xsT) {
    int w = threadIdx.x >> 6;
    int lane = threadIdx.x & 63;
    int bi = blockIdx.x * 4 + w;
    if (bi >= Bb * Nn) return;
    int b = (bi >= Nn) ? 1 : 0;
    int i = bi - b * Nn;
    const float* Arow = A + (size_t)bi * Nn;
    short* Brow = (short*)Abf + (size_t)bi * Nn;
    float s = 0.f;
#pragma unroll
    for (int it = 0; it < 6; ++it) {
        int j = it * 256 + lane * 4;
        float4 a4 = *reinterpret_cast<const float4*>(Arow + j);
        s += a4.x + a4.y + a4.z + a4.w;
        float e0 = (j + 0 == i) ? ((a4.x == 0.f) ? 1.f : a4.x) : a4.x;
        float e1 = (j + 1 == i) ? ((a4.y == 0.f) ? 1.f : a4.y) : a4.y;
        float e2v = (j + 2 == i) ? ((a4.z == 0.f) ? 1.f : a4.z) : a4.z;
        float e3v = (j + 3 == i) ? ((a4.w == 0.f) ? 1.f : a4.w) : a4.w;
        short4v sv = { f2bf(e0), f2bf(e1), f2bf(e2v), f2bf(e3v) };
        *reinterpret_cast<short4v*>(Brow + j) = sv;
    }
#pragma unroll
    for (int o = 1; o < 64; o <<= 1) s += __shfl_xor(s, o, 64);
    float d = Arow[i];
    float fill = (d == 0.f) ? 1.f : d;
    float deg = s - d + fill;
    float di = (deg > 0.f) ? (1.f / sqrtf(deg)) : 0.f;
    if (lane == 0) dinv[bi] = di;
    if (lane < 32) {
        float acc = 0.f;
#pragma unroll
        for (int m = 0; m < 8; ++m)
            acc = fmaf(emb[(size_t)i * 8 + m], W1[m * Hh + lane], acc);
        ((short*)xsT)[(size_t)(b * Hh + lane) * Nn + i] = f2bf(di * acc);
    }
}

// ---------------- GCN propagation via MFMA + fused epilogues ----------------
__global__ __launch_bounds__(256, 1) void prop_kernel(
    const __hip_bfloat16* __restrict__ Abf, const __hip_bfloat16* __restrict__ xsT,
    const float* __restrict__ dinv, const float* __restrict__ bias,
    const float* __restrict__ res, float* __restrict__ out, int has_res,
    const float* __restrict__ Wn, __hip_bfloat16* __restrict__ xsT_next,
    int final_stage,
    const float* __restrict__ Wmu, const float* __restrict__ bmu,
    const float* __restrict__ Wlv, const float* __restrict__ blv,
    const float* __restrict__ E1, const float* __restrict__ e1,
    float* __restrict__ mu, float* __restrict__ lv,
    _Float16* __restrict__ Uh, _Float16* __restrict__ Vh) {
    __shared__ float sRed[4][64][8];
    __shared__ float sOut[16][33];
    __shared__ float sWn[32][32];
    __shared__ float sMu[16][16];
    int t = threadIdx.x, lane = t & 63, w = t >> 6;
    int x = lane & 15, g = lane >> 4;
    int mt = blockIdx.x;
    int b = mt / Nb, it = mt - b * Nb;
    int i0 = it * 16;

    if (Wn) {
        for (int k = t; k < 1024; k += 256) sWn[k >> 5][k & 31] = Wn[k];
    }

    const short* Arow = (const short*)Abf + ((size_t)b * Nn + i0 + x) * Nn + 8 * g;
    const short* X0 = (const short*)xsT + ((size_t)(b * Hh) + x) * Nn + 8 * g;
    const short* X1 = X0 + (size_t)16 * Nn;

    f32x4 acc0 = {0.f, 0.f, 0.f, 0.f};
    f32x4 acc1 = {0.f, 0.f, 0.f, 0.f};
    int ks0 = w * (KSTEPS / 4);
#pragma unroll
    for (int ks = ks0; ks < ks0 + KSTEPS / 4; ++ks) {
        bf16x8 af = *reinterpret_cast<const bf16x8*>(Arow + ks * 32);
        bf16x8 b0 = *reinterpret_cast<const bf16x8*>(X0 + ks * 32);
        bf16x8 b1 = *reinterpret_cast<const bf16x8*>(X1 + ks * 32);
        acc0 = __builtin_amdgcn_mfma_f32_16x16x32_bf16(af, b0, acc0, 0, 0, 0);
        acc1 = __builtin_amdgcn_mfma_f32_16x16x32_bf16(af, b1, acc1, 0, 0, 0);
    }
#pragma unroll
    for (int r = 0; r < 4; ++r) { sRed[w][lane][r] = acc0[r]; sRed[w][lane][4 + r] = acc1[r]; }
    __syncthreads();

    int xx = lane & 15, gg = lane >> 4;
#pragma unroll
    for (int q = 0; q < 2; ++q) {
        int ri = w * 2 + q;
        float v = sRed[0][lane][ri] + sRed[1][lane][ri] + sRed[2][lane][ri] + sRed[3][lane][ri];
        int row = 4 * gg + (ri & 3);
        int c = (ri < 4) ? xx : (16 + xx);
        int bi = b * Nn + i0 + row;
        v = dinv[bi] * v + bias[c];
        v = fmaxf(v, 0.f);
        if (has_res) v += res[(size_t)bi * Hh + c];
        out[(size_t)bi * Hh + c] = v;
        sOut[row][c] = v;
    }
    __syncthreads();

    if (Wn) {
        for (int k = t; k < 512; k += 256) {
            int r = k >> 5, c = k & 31;
            float acc = 0.f;
#pragma unroll
            for (int m = 0; m < 32; ++m) acc = fmaf(sOut[r][m], sWn[m][c], acc);
            int bi = b * Nn + i0 + r;
            ((short*)xsT_next)[(size_t)(b * Hh + c) * Nn + i0 + r] = f2bf(dinv[bi] * acc);
        }
    }
    if (final_stage) {
        {
            int r = t >> 4, ll = t & 15;
            float am = bmu[ll], av = blv[ll];
#pragma unroll
            for (int m = 0; m < 32; ++m) {
                float hv = sOut[r][m];
                am = fmaf(hv, Wmu[m * Ll + ll], am);
                av = fmaf(hv, Wlv[m * Ll + ll], av);
            }
            size_t o = ((size_t)b * Nn + i0 + r) * Ll + ll;
            mu[o] = am; lv[o] = av;
            sMu[r][ll] = am;
        }
        __syncthreads();
#pragma unroll
        for (int q = 0; q < 4; ++q) {
            int idx = q * 256 + t;
            int r = idx >> 6, c = idx & 63;
            float ua = e1[c], va = 0.f;
#pragma unroll
            for (int m = 0; m < Ll; ++m) {
                float zm = sMu[r][m];
                ua = fmaf(zm, E1[m * 64 + c], ua);
                va = fmaf(zm, E1[(16 + m) * 64 + c], va);
            }
            size_t o = ((size_t)b * Nn + i0 + r) * 64 + c;
            Uh[o] = (_Float16)ua;
            Vh[o] = (_Float16)va;
        }
    }
}

// ---------------- edge MLP: HALF-region (8 rows) per wave; 2 regions per block ----------------
// Waves 2s, 2s+1 handle rows 0-7 / 8-15 of region slot s; mirror tile shared via LDS.
__global__ __launch_bounds__(256) void edge_kernel(
    const _Float16* __restrict__ Uh, const _Float16* __restrict__ Vh,
    const float* __restrict__ E2, const float* __restrict__ e2,
    const float* __restrict__ E3, const float* __restrict__ e3,
    float* __restrict__ adj) {
    __shared__ float sW[2][16][20];
    int t = threadIdx.x, lane = t & 63, w = t >> 6;
    int x = lane & 15, g = lane >> 4;
    int s = w >> 1;          // region slot (0,1)
    int h = w & 1;           // row half
    int rbase = h * 8;

    // ---- per-wave invariants ----
    f16x8 ea[2][2];
#pragma unroll
    for (int ct = 0; ct < 2; ++ct)
#pragma unroll
        for (int ks = 0; ks < 2; ++ks)
#pragma unroll
            for (int jj = 0; jj < 8; ++jj)
                ea[ct][ks][jj] = (_Float16)E2[(32 * ks + 8 * g + jj) * Hh + 16 * ct + x];

    float e2a[4], e2b[4], E3a[4], E3b[4];
#pragma unroll
    for (int rg = 0; rg < 4; ++rg) {
        e2a[rg] = e2[4 * g + rg];      E3a[rg] = E3[4 * g + rg];
        e2b[rg] = e2[16 + 4 * g + rg]; E3b[rg] = E3[16 + 4 * g + rg];
    }
    float e3s = e3[0];

    // ---- region index ----
    int tr = blockIdx.x * 2 + s;
    int b = 0;
    if (tr >= TREG) { b = 1; tr -= TREG; }
    float ft = (float)tr;
    int ib = (int)((193.0f - sqrtf(193.0f * 193.0f - 8.0f * ft)) * 0.5f);
    ib = ib < 0 ? 0 : (ib > Nb - 1 ? Nb - 1 : ib);
    while (ib < Nb - 1 && (ib + 1) * Nb - ((ib + 1) * ib) / 2 <= tr) ++ib;
    while (ib > 0 && ib * Nb - (ib * (ib - 1)) / 2 > tr) --ib;
    int jb = ib + (tr - (ib * Nb - (ib * (ib - 1)) / 2));
    int i0 = ib * 16, j0 = jb * 16;
    bool diag = (ib == jb);

    const f16x8* Vrow = reinterpret_cast<const f16x8*>(Vh + ((size_t)b * Nn + j0 + x) * 64);
    f16x8 vf0 = Vrow[g];
    f16x8 vf1 = Vrow[4 + g];

    const f16x8* Ubase = reinterpret_cast<const f16x8*>(Uh + ((size_t)b * Nn + i0) * 64);

    if (diag && h == 0 && lane < 16) sW[s][lane][lane] = 0.f;

    const f16x8 fz = {0, 0, 0, 0, 0, 0, 0, 0};

    // phase 1: 8 rows of MFMA + lane-local partial (pure dataflow, rows independent)
    float part[8];
#pragma unroll 4
    for (int r = 0; r < 8; ++r) {
        int rg16 = rbase + r;
        f16x8 u0 = Ubase[rg16 * 8 + g];
        f16x8 u1 = Ubase[rg16 * 8 + 4 + g];
        f16x8 af0 = __builtin_elementwise_max(u0 + vf0, fz);
        f16x8 af1 = __builtin_elementwise_max(u1 + vf1, fz);

        f32x4 acc0 = {e2a[0], e2a[1], e2a[2], e2a[3]};
        f32x4 acc1 = {e2b[0], e2b[1], e2b[2], e2b[3]};
        acc0 = __builtin_amdgcn_mfma_f32_16x16x32_f16(ea[0][0], af0, acc0, 0, 0, 0);
        acc0 = __builtin_amdgcn_mfma_f32_16x16x32_f16(ea[0][1], af1, acc0, 0, 0, 0);
        acc1 = __builtin_amdgcn_mfma_f32_16x16x32_f16(ea[1][0], af0, acc1, 0, 0, 0);
        acc1 = __builtin_amdgcn_mfma_f32_16x16x32_f16(ea[1][1], af1, acc1, 0, 0, 0);

        float p = 0.f;
#pragma unroll
        for (int rg = 0; rg < 4; ++rg) {
            p = fmaf(fmaxf(acc0[rg], 0.f), E3a[rg], p);
            p = fmaf(fmaxf(acc1[rg], 0.f), E3b[rg], p);
        }
        part[r] = p;
    }

    // phase 2: batched cross-lane reduce (independent chains)
#pragma unroll
    for (int r = 0; r < 8; ++r) part[r] += permswap32(part[r]);
#pragma unroll
    for (int r = 0; r < 8; ++r) part[r] += permswap16(part[r]);

    // phase 3: batched sigmoid
    float wv[8];
#pragma unroll
    for (int r = 0; r < 8; ++r) {
        float logit = part[r] + e3s;
        wv[r] = __builtin_amdgcn_rcpf(1.f + __expf(-logit));
    }

    // phase 4: direct stores + mirror staging (lanes 0-15 hold valid sums)
    if (g == 0) {
#pragma unroll
        for (int r = 0; r < 8; ++r) {
            int rg16 = rbase + r;
            if (!diag) {
                adj[((size_t)b * Nn + i0 + rg16) * Nn + j0 + x] = wv[r];
                sW[s][x][rg16] = wv[r];
            } else if (x > rg16) {
                sW[s][rg16][x] = wv[r];
                sW[s][x][rg16] = wv[r];
            }
        }
    }
    __syncthreads();

    // phase 5: mirrored-tile store; wave (s,h) stores rows rbase..rbase+7 of slot s
    if (lane < 32) {
        int rr = rbase + (lane >> 2), m4 = (lane & 3) * 4;
        float4 wv4 = *reinterpret_cast<const float4*>(&sW[s][rr][m4]);
        if (!diag)
            *reinterpret_cast<float4*>(&adj[((size_t)b * Nn + j0 + rr) * Nn + i0 + m4]) = wv4;
        else
            *reinterpret_cast<float4*>(&adj[((size_t)b * Nn + i0 + rr) * Nn + i0 + m4]) = wv4;
    }
}

extern "C" void kernel_launch(void* const* d_in, const int* in_sizes, int n_in,
                              void* d_out, int out_size, void* d_ws, size_t ws_size,
                              hipStream_t stream) {
    const float* A   = (const float*)d_in[0];
    const float* emb = (const float*)d_in[1];
    const float* W1  = (const float*)d_in[2];  const float* b1  = (const float*)d_in[3];
    const float* W2  = (const float*)d_in[4];  const float* b2  = (const float*)d_in[5];
    const float* W3  = (const float*)d_in[6];  const float* b3  = (const float*)d_in[7];
    const float* Wmu = (const float*)d_in[8];  const float* bmu = (const float*)d_in[9];
    const float* Wlv = (const float*)d_in[10]; const float* blv = (const float*)d_in[11];
    const float* E1  = (const float*)d_in[12]; const float* e1  = (const float*)d_in[13];
    const float* E2  = (const float*)d_in[14]; const float* e2  = (const float*)d_in[15];
    const float* E3  = (const float*)d_in[16]; const float* e3  = (const float*)d_in[17];

    float* out = (float*)d_out;
    float* ws  = (float*)d_ws;
    float* dinv = ws;
    float* hA   = ws + 3072;
    float* hB   = ws + 101376;
    __hip_bfloat16* xsTa = (__hip_bfloat16*)(ws + 199680);
    __hip_bfloat16* xsTb = (__hip_bfloat16*)(ws + 248832);
    _Float16* Uh = (_Float16*)(ws + 297984);
    _Float16* Vh = (_Float16*)(ws + 396288);
    __hip_bfloat16* Abf = (__hip_bfloat16*)out;   // aliases adj region; overwritten by edge later

    float* mu_out = out + (size_t)Bb * Nn * Nn;
    float* lv_out = mu_out + (size_t)Bb * Nn * Ll;

    prep_kernel<<<(Bb * Nn + 3) / 4, 256, 0, stream>>>(A, Abf, dinv, emb, W1, xsTa);

    prop_kernel<<<Bb * Nb, 256, 0, stream>>>(Abf, xsTa, dinv, b1, nullptr, hA, 0,
                                             W2, xsTb, 0,
                                             nullptr, nullptr, nullptr, nullptr,
                                             nullptr, nullptr, nullptr, nullptr,
                                             nullptr, nullptr);
    prop_kernel<<<Bb * Nb, 256, 0, stream>>>(Abf, xsTb, dinv, b2, hA, hB, 1,
                                             W3, xsTa, 0,
                                             nullptr, nullptr, nullptr, nullptr,
                                             nullptr, nullptr, nullptr, nullptr,
                                             nullptr, nullptr);
    prop_kernel<<<Bb * Nb, 256, 0, stream>>>(Abf, xsTa, dinv, b3, hB, hA, 1,
                                             nullptr, nullptr, 1,
                                             Wmu, bmu, Wlv, blv, E1, e1,
                                             mu_out, lv_out, Uh, Vh);

    // 9312 regions, 2 per block (one per wave-pair) -> 4656 blocks
    edge_kernel<<<TREG, 256, 0, stream>>>(Uh, Vh, E2, e2, E3, e3, out);
}

// Round 12
// 67.291 us; speedup vs baseline: 2.0629x; 1.1443x over previous
//
#include <hip/hip_runtime.h>
#include <hip/hip_bf16.h>
#include <math.h>

#define Nn 1536
#define Bb 2
#define Hh 32
#define Ll 16
#define Nb 96          // Nn/16
#define TREG 4656      // Nb*(Nb+1)/2 regions per batch
#define KSTEPS 48      // 1536/32

typedef short bf16x8 __attribute__((ext_vector_type(8)));
typedef _Float16 f16x8 __attribute__((ext_vector_type(8)));
typedef float f32x4 __attribute__((ext_vector_type(4)));
typedef short short4v __attribute__((ext_vector_type(4)));

__device__ __forceinline__ short f2bf(float x) {
    __hip_bfloat16 h = __float2bfloat16(x);
    return *reinterpret_cast<short*>(&h);
}

// VALU half-swaps (gfx950). Result valid in the LOWER half of each swap domain.
__device__ __forceinline__ float permswap32(float v) {
    float a = v, b = v;
    asm("v_permlane32_swap_b32 %0, %1" : "+v"(a), "+v"(b));
    return a;
}
__device__ __forceinline__ float permswap16(float v) {
    float a = v, b = v;
    asm("v_permlane16_swap_b32 %0, %1" : "+v"(a), "+v"(b));
    return a;
}

// ---------------- prep: rowsum -> dinv, A -> bf16 with self-loop fill, fused layer-1 xsT ----------------
__global__ void prep_kernel(const float* __restrict__ A,
                            __hip_bfloat16* __restrict__ Abf,
                            float* __restrict__ dinv,
                            const float* __restrict__ emb,
                            const float* __restrict__ W1,
                            __hip_bfloat16* __restrict__ xsT) {
    int w = threadIdx.x >> 6;
    int lane = threadIdx.x & 63;
    int bi = blockIdx.x * 4 + w;
    if (bi >= Bb * Nn) return;
    int b = (bi >= Nn) ? 1 : 0;
    int i = bi - b * Nn;
    const float* Arow = A + (size_t)bi * Nn;
    short* Brow = (short*)Abf + (size_t)bi * Nn;
    float s = 0.f;
#pragma unroll
    for (int it = 0; it < 6; ++it) {
        int j = it * 256 + lane * 4;
        float4 a4 = *reinterpret_cast<const float4*>(Arow + j);
        s += a4.x + a4.y + a4.z + a4.w;
        float e0 = (j + 0 == i) ? ((a4.x == 0.f) ? 1.f : a4.x) : a4.x;
        float e1 = (j + 1 == i) ? ((a4.y == 0.f) ? 1.f : a4.y) : a4.y;
        float e2v = (j + 2 == i) ? ((a4.z == 0.f) ? 1.f : a4.z) : a4.z;
        float e3v = (j + 3 == i) ? ((a4.w == 0.f) ? 1.f : a4.w) : a4.w;
        short4v sv = { f2bf(e0), f2bf(e1), f2bf(e2v), f2bf(e3v) };
        *reinterpret_cast<short4v*>(Brow + j) = sv;
    }
#pragma unroll
    for (int o = 1; o < 64; o <<= 1) s += __shfl_xor(s, o, 64);
    float d = Arow[i];
    float fill = (d == 0.f) ? 1.f : d;
    float deg = s - d + fill;
    float di = (deg > 0.f) ? (1.f / sqrtf(deg)) : 0.f;
    if (lane == 0) dinv[bi] = di;
    if (lane < 32) {
        float acc = 0.f;
#pragma unroll
        for (int m = 0; m < 8; ++m)
            acc = fmaf(emb[(size_t)i * 8 + m], W1[m * Hh + lane], acc);
        ((short*)xsT)[(size_t)(b * Hh + lane) * Nn + i] = f2bf(di * acc);
    }
}

// ---------------- GCN propagation via MFMA + fused epilogues ----------------
__global__ __launch_bounds__(256, 1) void prop_kernel(
    const __hip_bfloat16* __restrict__ Abf, const __hip_bfloat16* __restrict__ xsT,
    const float* __restrict__ dinv, const float* __restrict__ bias,
    const float* __restrict__ res, float* __restrict__ out, int has_res,
    const float* __restrict__ Wn, __hip_bfloat16* __restrict__ xsT_next,
    int final_stage,
    const float* __restrict__ Wmu, const float* __restrict__ bmu,
    const float* __restrict__ Wlv, const float* __restrict__ blv,
    const float* __restrict__ E1, const float* __restrict__ e1,
    float* __restrict__ mu, float* __restrict__ lv,
    _Float16* __restrict__ Uh, _Float16* __restrict__ Vh) {
    __shared__ float sRed[4][64][8];
    __shared__ float sOut[16][33];
    __shared__ float sWn[32][32];
    __shared__ float sMu[16][16];
    int t = threadIdx.x, lane = t & 63, w = t >> 6;
    int x = lane & 15, g = lane >> 4;
    int mt = blockIdx.x;
    int b = mt / Nb, it = mt - b * Nb;
    int i0 = it * 16;

    if (Wn) {
        for (int k = t; k < 1024; k += 256) sWn[k >> 5][k & 31] = Wn[k];
    }

    const short* Arow = (const short*)Abf + ((size_t)b * Nn + i0 + x) * Nn + 8 * g;
    const short* X0 = (const short*)xsT + ((size_t)(b * Hh) + x) * Nn + 8 * g;
    const short* X1 = X0 + (size_t)16 * Nn;

    f32x4 acc0 = {0.f, 0.f, 0.f, 0.f};
    f32x4 acc1 = {0.f, 0.f, 0.f, 0.f};
    int ks0 = w * (KSTEPS / 4);
#pragma unroll
    for (int ks = ks0; ks < ks0 + KSTEPS / 4; ++ks) {
        bf16x8 af = *reinterpret_cast<const bf16x8*>(Arow + ks * 32);
        bf16x8 b0 = *reinterpret_cast<const bf16x8*>(X0 + ks * 32);
        bf16x8 b1 = *reinterpret_cast<const bf16x8*>(X1 + ks * 32);
        acc0 = __builtin_amdgcn_mfma_f32_16x16x32_bf16(af, b0, acc0, 0, 0, 0);
        acc1 = __builtin_amdgcn_mfma_f32_16x16x32_bf16(af, b1, acc1, 0, 0, 0);
    }
#pragma unroll
    for (int r = 0; r < 4; ++r) { sRed[w][lane][r] = acc0[r]; sRed[w][lane][4 + r] = acc1[r]; }
    __syncthreads();

    int xx = lane & 15, gg = lane >> 4;
#pragma unroll
    for (int q = 0; q < 2; ++q) {
        int ri = w * 2 + q;
        float v = sRed[0][lane][ri] + sRed[1][lane][ri] + sRed[2][lane][ri] + sRed[3][lane][ri];
        int row = 4 * gg + (ri & 3);
        int c = (ri < 4) ? xx : (16 + xx);
        int bi = b * Nn + i0 + row;
        v = dinv[bi] * v + bias[c];
        v = fmaxf(v, 0.f);
        if (has_res) v += res[(size_t)bi * Hh + c];
        out[(size_t)bi * Hh + c] = v;
        sOut[row][c] = v;
    }
    __syncthreads();

    if (Wn) {
        for (int k = t; k < 512; k += 256) {
            int r = k >> 5, c = k & 31;
            float acc = 0.f;
#pragma unroll
            for (int m = 0; m < 32; ++m) acc = fmaf(sOut[r][m], sWn[m][c], acc);
            int bi = b * Nn + i0 + r;
            ((short*)xsT_next)[(size_t)(b * Hh + c) * Nn + i0 + r] = f2bf(dinv[bi] * acc);
        }
    }
    if (final_stage) {
        {
            int r = t >> 4, ll = t & 15;
            float am = bmu[ll], av = blv[ll];
#pragma unroll
            for (int m = 0; m < 32; ++m) {
                float hv = sOut[r][m];
                am = fmaf(hv, Wmu[m * Ll + ll], am);
                av = fmaf(hv, Wlv[m * Ll + ll], av);
            }
            size_t o = ((size_t)b * Nn + i0 + r) * Ll + ll;
            mu[o] = am; lv[o] = av;
            sMu[r][ll] = am;
        }
        __syncthreads();
#pragma unroll
        for (int q = 0; q < 4; ++q) {
            int idx = q * 256 + t;
            int r = idx >> 6, c = idx & 63;
            float ua = e1[c], va = 0.f;
#pragma unroll
            for (int m = 0; m < Ll; ++m) {
                float zm = sMu[r][m];
                ua = fmaf(zm, E1[m * 64 + c], ua);
                va = fmaf(zm, E1[(16 + m) * 64 + c], va);
            }
            size_t o = ((size_t)b * Nn + i0 + r) * 64 + c;
            Uh[o] = (_Float16)ua;
            Vh[o] = (_Float16)va;
        }
    }
}

// ---------------- edge MLP: full 16-row region per wave, LDS-staged E2/bias, deferred tail ----------------
__global__ __launch_bounds__(256) void edge_kernel(
    const _Float16* __restrict__ Uh, const _Float16* __restrict__ Vh,
    const float* __restrict__ E2, const float* __restrict__ e2,
    const float* __restrict__ E3, const float* __restrict__ e3,
    float* __restrict__ adj) {
    __shared__ _Float16 sE2T[2][2][4][16][8];   // 4 KB: [ct][ks][g][x][jj] pre-transposed E2
    __shared__ float sBias[65];                 // e2[32] | E3[32] | e3
    __shared__ float sW[4][16][20];             // 5 KB: mirror tile staging
    int t = threadIdx.x, lane = t & 63, w = t >> 6;
    int x = lane & 15, g = lane >> 4;

    // ---- block-level staging (one coalesced pass, replaces per-wave scalar prologue) ----
    {
        int ct = t >> 7, ks = (t >> 6) & 1, gg = (t >> 4) & 3, xx = t & 15;
#pragma unroll
        for (int jj = 0; jj < 8; ++jj)
            sE2T[ct][ks][gg][xx][jj] = (_Float16)E2[(32 * ks + 8 * gg + jj) * Hh + 16 * ct + xx];
    }
    if (t < 32) sBias[t] = e2[t];
    else if (t < 64) sBias[t] = E3[t - 32];
    else if (t == 64) sBias[64] = e3[0];
    __syncthreads();

    // per-wave invariants from LDS (4x ds_read_b128 + 17 scalar LDS reads)
    f16x8 ea[2][2];
#pragma unroll
    for (int ct = 0; ct < 2; ++ct)
#pragma unroll
        for (int ks = 0; ks < 2; ++ks)
            ea[ct][ks] = *reinterpret_cast<const f16x8*>(&sE2T[ct][ks][g][x][0]);

    float e2a[4], e2b[4], E3a[4], E3b[4];
#pragma unroll
    for (int rg = 0; rg < 4; ++rg) {
        e2a[rg] = sBias[4 * g + rg];      E3a[rg] = sBias[32 + 4 * g + rg];
        e2b[rg] = sBias[16 + 4 * g + rg]; E3b[rg] = sBias[48 + 4 * g + rg];
    }
    float e3s = sBias[64];

    // ---- region index: one full region per wave ----
    int tr = blockIdx.x * 4 + w;
    int b = 0;
    if (tr >= TREG) { b = 1; tr -= TREG; }
    float ft = (float)tr;
    int ib = (int)((193.0f - sqrtf(193.0f * 193.0f - 8.0f * ft)) * 0.5f);
    ib = ib < 0 ? 0 : (ib > Nb - 1 ? Nb - 1 : ib);
    while (ib < Nb - 1 && (ib + 1) * Nb - ((ib + 1) * ib) / 2 <= tr) ++ib;
    while (ib > 0 && ib * Nb - (ib * (ib - 1)) / 2 > tr) --ib;
    int jb = ib + (tr - (ib * Nb - (ib * (ib - 1)) / 2));
    int i0 = ib * 16, j0 = jb * 16;
    bool diag = (ib == jb);

    const f16x8* Vrow = reinterpret_cast<const f16x8*>(Vh + ((size_t)b * Nn + j0 + x) * 64);
    f16x8 vf0 = Vrow[g];
    f16x8 vf1 = Vrow[4 + g];

    const f16x8* Ubase = reinterpret_cast<const f16x8*>(Uh + ((size_t)b * Nn + i0) * 64);

    if (diag && lane < 16) sW[w][lane][lane] = 0.f;

    const f16x8 fz = {0, 0, 0, 0, 0, 0, 0, 0};

    // phase 1: per-row MFMA + lane-local partial (pure dataflow, fully unrolled)
    float part[16];
#pragma unroll
    for (int r = 0; r < 16; ++r) {
        f16x8 u0 = Ubase[r * 8 + g];
        f16x8 u1 = Ubase[r * 8 + 4 + g];
        f16x8 af0 = __builtin_elementwise_max(u0 + vf0, fz);
        f16x8 af1 = __builtin_elementwise_max(u1 + vf1, fz);

        f32x4 acc0 = {e2a[0], e2a[1], e2a[2], e2a[3]};
        f32x4 acc1 = {e2b[0], e2b[1], e2b[2], e2b[3]};
        acc0 = __builtin_amdgcn_mfma_f32_16x16x32_f16(ea[0][0], af0, acc0, 0, 0, 0);
        acc0 = __builtin_amdgcn_mfma_f32_16x16x32_f16(ea[0][1], af1, acc0, 0, 0, 0);
        acc1 = __builtin_amdgcn_mfma_f32_16x16x32_f16(ea[1][0], af0, acc1, 0, 0, 0);
        acc1 = __builtin_amdgcn_mfma_f32_16x16x32_f16(ea[1][1], af1, acc1, 0, 0, 0);

        float p = 0.f;
#pragma unroll
        for (int rg = 0; rg < 4; ++rg) {
            p = fmaf(fmaxf(acc0[rg], 0.f), E3a[rg], p);
            p = fmaf(fmaxf(acc1[rg], 0.f), E3b[rg], p);
        }
        part[r] = p;
    }

    // phase 2: batched cross-lane reduce (independent chains)
#pragma unroll
    for (int r = 0; r < 16; ++r) part[r] += permswap32(part[r]);
#pragma unroll
    for (int r = 0; r < 16; ++r) part[r] += permswap16(part[r]);

    // phase 3: batched sigmoid
    float wv[16];
#pragma unroll
    for (int r = 0; r < 16; ++r) {
        float logit = part[r] + e3s;
        wv[r] = __builtin_amdgcn_rcpf(1.f + __expf(-logit));
    }

    // phase 4: stores (lanes 0-15 hold valid sums)
    if (g == 0) {
#pragma unroll
        for (int r = 0; r < 16; ++r) {
            if (!diag) {
                adj[((size_t)b * Nn + i0 + r) * Nn + j0 + x] = wv[r];
                sW[w][x][r] = wv[r];
            } else if (x > r) {
                sW[w][r][x] = wv[r];
                sW[w][x][r] = wv[r];
            }
        }
    }

    // phase 5: region-level coalesced store of the mirrored tile (same-wave LDS, no barrier)
    {
        int rr = lane >> 2, m4 = (lane & 3) * 4;
        float4 wv4 = *reinterpret_cast<const float4*>(&sW[w][rr][m4]);
        if (!diag)
            *reinterpret_cast<float4*>(&adj[((size_t)b * Nn + j0 + rr) * Nn + i0 + m4]) = wv4;
        else
            *reinterpret_cast<float4*>(&adj[((size_t)b * Nn + i0 + rr) * Nn + i0 + m4]) = wv4;
    }
}

extern "C" void kernel_launch(void* const* d_in, const int* in_sizes, int n_in,
                              void* d_out, int out_size, void* d_ws, size_t ws_size,
                              hipStream_t stream) {
    const float* A   = (const float*)d_in[0];
    const float* emb = (const float*)d_in[1];
    const float* W1  = (const float*)d_in[2];  const float* b1  = (const float*)d_in[3];
    const float* W2  = (const float*)d_in[4];  const float* b2  = (const float*)d_in[5];
    const float* W3  = (const float*)d_in[6];  const float* b3  = (const float*)d_in[7];
    const float* Wmu = (const float*)d_in[8];  const float* bmu = (const float*)d_in[9];
    const float* Wlv = (const float*)d_in[10]; const float* blv = (const float*)d_in[11];
    const float* E1  = (const float*)d_in[12]; const float* e1  = (const float*)d_in[13];
    const float* E2  = (const float*)d_in[14]; const float* e2  = (const float*)d_in[15];
    const float* E3  = (const float*)d_in[16]; const float* e3  = (const float*)d_in[17];

    float* out = (float*)d_out;
    float* ws  = (float*)d_ws;
    float* dinv = ws;
    float* hA   = ws + 3072;
    float* hB   = ws + 101376;
    __hip_bfloat16* xsTa = (__hip_bfloat16*)(ws + 199680);
    __hip_bfloat16* xsTb = (__hip_bfloat16*)(ws + 248832);
    _Float16* Uh = (_Float16*)(ws + 297984);
    _Float16* Vh = (_Float16*)(ws + 396288);
    __hip_bfloat16* Abf = (__hip_bfloat16*)out;   // aliases adj region; overwritten by edge later

    float* mu_out = out + (size_t)Bb * Nn * Nn;
    float* lv_out = mu_out + (size_t)Bb * Nn * Ll;

    prep_kernel<<<(Bb * Nn + 3) / 4, 256, 0, stream>>>(A, Abf, dinv, emb, W1, xsTa);

    prop_kernel<<<Bb * Nb, 256, 0, stream>>>(Abf, xsTa, dinv, b1, nullptr, hA, 0,
                                             W2, xsTb, 0,
                                             nullptr, nullptr, nullptr, nullptr,
                                             nullptr, nullptr, nullptr, nullptr,
                                             nullptr, nullptr);
    prop_kernel<<<Bb * Nb, 256, 0, stream>>>(Abf, xsTb, dinv, b2, hA, hB, 1,
                                             W3, xsTa, 0,
                                             nullptr, nullptr, nullptr, nullptr,
                                             nullptr, nullptr, nullptr, nullptr,
                                             nullptr, nullptr);
    prop_kernel<<<Bb * Nb, 256, 0, stream>>>(Abf, xsTa, dinv, b3, hB, hA, 1,
                                             nullptr, nullptr, 1,
                                             Wmu, bmu, Wlv, blv, E1, e1,
                                             mu_out, lv_out, Uh, Vh);

    // 9312 regions, one per wave -> 2328 blocks
    edge_kernel<<<(2 * TREG) / 4, 256, 0, stream>>>(Uh, Vh, E2, e2, E3, e3, out);
}

// Round 13
// 66.966 us; speedup vs baseline: 2.0729x; 1.0048x over previous
//
#include <hip/hip_runtime.h>
#include <hip/hip_bf16.h>
#include <math.h>

#define Nn 1536
#define Bb 2
#define Hh 32
#define Ll 16
#define Nb 96          // Nn/16
#define TREG 4656      // Nb*(Nb+1)/2 regions per batch
#define KSTEPS 48      // 1536/32

typedef short bf16x8 __attribute__((ext_vector_type(8)));
typedef _Float16 f16x8 __attribute__((ext_vector_type(8)));
typedef float f32x4 __attribute__((ext_vector_type(4)));
typedef short short4v __attribute__((ext_vector_type(4)));

__device__ __forceinline__ short f2bf(float x) {
    __hip_bfloat16 h = __float2bfloat16(x);
    return *reinterpret_cast<short*>(&h);
}

// VALU half-swaps (gfx950). Result valid in the LOWER half of each swap domain.
__device__ __forceinline__ float permswap32(float v) {
    float a = v, b = v;
    asm("v_permlane32_swap_b32 %0, %1" : "+v"(a), "+v"(b));
    return a;
}
__device__ __forceinline__ float permswap16(float v) {
    float a = v, b = v;
    asm("v_permlane16_swap_b32 %0, %1" : "+v"(a), "+v"(b));
    return a;
}

// ---------------- prep: rowsum -> dinv, A -> bf16 with self-loop fill, fused layer-1 xsT ----------------
__global__ void prep_kernel(const float* __restrict__ A,
                            __hip_bfloat16* __restrict__ Abf,
                            float* __restrict__ dinv,
                            const float* __restrict__ emb,
                            const float* __restrict__ W1,
                            __hip_bfloat16* __restrict__ xsT) {
    int w = threadIdx.x >> 6;
    int lane = threadIdx.x & 63;
    int bi = blockIdx.x * 4 + w;
    if (bi >= Bb * Nn) return;
    int b = (bi >= Nn) ? 1 : 0;
    int i = bi - b * Nn;
    const float* Arow = A + (size_t)bi * Nn;
    short* Brow = (short*)Abf + (size_t)bi * Nn;
    float s = 0.f;
#pragma unroll
    for (int it = 0; it < 6; ++it) {
        int j = it * 256 + lane * 4;
        float4 a4 = *reinterpret_cast<const float4*>(Arow + j);
        s += a4.x + a4.y + a4.z + a4.w;
        float e0 = (j + 0 == i) ? ((a4.x == 0.f) ? 1.f : a4.x) : a4.x;
        float e1 = (j + 1 == i) ? ((a4.y == 0.f) ? 1.f : a4.y) : a4.y;
        float e2v = (j + 2 == i) ? ((a4.z == 0.f) ? 1.f : a4.z) : a4.z;
        float e3v = (j + 3 == i) ? ((a4.w == 0.f) ? 1.f : a4.w) : a4.w;
        short4v sv = { f2bf(e0), f2bf(e1), f2bf(e2v), f2bf(e3v) };
        *reinterpret_cast<short4v*>(Brow + j) = sv;
    }
#pragma unroll
    for (int o = 1; o < 64; o <<= 1) s += __shfl_xor(s, o, 64);
    float d = Arow[i];
    float fill = (d == 0.f) ? 1.f : d;
    float deg = s - d + fill;
    float di = (deg > 0.f) ? (1.f / sqrtf(deg)) : 0.f;
    if (lane == 0) dinv[bi] = di;
    if (lane < 32) {
        float acc = 0.f;
#pragma unroll
        for (int m = 0; m < 8; ++m)
            acc = fmaf(emb[(size_t)i * 8 + m], W1[m * Hh + lane], acc);
        ((short*)xsT)[(size_t)(b * Hh + lane) * Nn + i] = f2bf(di * acc);
    }
}

// ---------------- GCN propagation via MFMA + fused epilogues ----------------
__global__ __launch_bounds__(256, 1) void prop_kernel(
    const __hip_bfloat16* __restrict__ Abf, const __hip_bfloat16* __restrict__ xsT,
    const float* __restrict__ dinv, const float* __restrict__ bias,
    const float* __restrict__ res, float* __restrict__ out, int has_res,
    const float* __restrict__ Wn, __hip_bfloat16* __restrict__ xsT_next,
    int final_stage,
    const float* __restrict__ Wmu, const float* __restrict__ bmu,
    const float* __restrict__ Wlv, const float* __restrict__ blv,
    const float* __restrict__ E1, const float* __restrict__ e1,
    float* __restrict__ mu, float* __restrict__ lv,
    _Float16* __restrict__ Uh, _Float16* __restrict__ Vh) {
    __shared__ float sRed[4][64][8];
    __shared__ float sOut[16][33];
    __shared__ float sWn[32][32];
    __shared__ float sMu[16][16];
    int t = threadIdx.x, lane = t & 63, w = t >> 6;
    int x = lane & 15, g = lane >> 4;
    int mt = blockIdx.x;
    int b = mt / Nb, it = mt - b * Nb;
    int i0 = it * 16;

    if (Wn) {
        for (int k = t; k < 1024; k += 256) sWn[k >> 5][k & 31] = Wn[k];
    }

    const short* Arow = (const short*)Abf + ((size_t)b * Nn + i0 + x) * Nn + 8 * g;
    const short* X0 = (const short*)xsT + ((size_t)(b * Hh) + x) * Nn + 8 * g;
    const short* X1 = X0 + (size_t)16 * Nn;

    f32x4 acc0 = {0.f, 0.f, 0.f, 0.f};
    f32x4 acc1 = {0.f, 0.f, 0.f, 0.f};
    int ks0 = w * (KSTEPS / 4);
#pragma unroll
    for (int ks = ks0; ks < ks0 + KSTEPS / 4; ++ks) {
        bf16x8 af = *reinterpret_cast<const bf16x8*>(Arow + ks * 32);
        bf16x8 b0 = *reinterpret_cast<const bf16x8*>(X0 + ks * 32);
        bf16x8 b1 = *reinterpret_cast<const bf16x8*>(X1 + ks * 32);
        acc0 = __builtin_amdgcn_mfma_f32_16x16x32_bf16(af, b0, acc0, 0, 0, 0);
        acc1 = __builtin_amdgcn_mfma_f32_16x16x32_bf16(af, b1, acc1, 0, 0, 0);
    }
#pragma unroll
    for (int r = 0; r < 4; ++r) { sRed[w][lane][r] = acc0[r]; sRed[w][lane][4 + r] = acc1[r]; }
    __syncthreads();

    int xx = lane & 15, gg = lane >> 4;
#pragma unroll
    for (int q = 0; q < 2; ++q) {
        int ri = w * 2 + q;
        float v = sRed[0][lane][ri] + sRed[1][lane][ri] + sRed[2][lane][ri] + sRed[3][lane][ri];
        int row = 4 * gg + (ri & 3);
        int c = (ri < 4) ? xx : (16 + xx);
        int bi = b * Nn + i0 + row;
        v = dinv[bi] * v + bias[c];
        v = fmaxf(v, 0.f);
        if (has_res) v += res[(size_t)bi * Hh + c];
        out[(size_t)bi * Hh + c] = v;
        sOut[row][c] = v;
    }
    __syncthreads();

    if (Wn) {
        for (int k = t; k < 512; k += 256) {
            int r = k >> 5, c = k & 31;
            float acc = 0.f;
#pragma unroll
            for (int m = 0; m < 32; ++m) acc = fmaf(sOut[r][m], sWn[m][c], acc);
            int bi = b * Nn + i0 + r;
            ((short*)xsT_next)[(size_t)(b * Hh + c) * Nn + i0 + r] = f2bf(dinv[bi] * acc);
        }
    }
    if (final_stage) {
        {
            int r = t >> 4, ll = t & 15;
            float am = bmu[ll], av = blv[ll];
#pragma unroll
            for (int m = 0; m < 32; ++m) {
                float hv = sOut[r][m];
                am = fmaf(hv, Wmu[m * Ll + ll], am);
                av = fmaf(hv, Wlv[m * Ll + ll], av);
            }
            size_t o = ((size_t)b * Nn + i0 + r) * Ll + ll;
            mu[o] = am; lv[o] = av;
            sMu[r][ll] = am;
        }
        __syncthreads();
#pragma unroll
        for (int q = 0; q < 4; ++q) {
            int idx = q * 256 + t;
            int r = idx >> 6, c = idx & 63;
            float ua = e1[c], va = 0.f;
#pragma unroll
            for (int m = 0; m < Ll; ++m) {
                float zm = sMu[r][m];
                ua = fmaf(zm, E1[m * 64 + c], ua);
                va = fmaf(zm, E1[(16 + m) * 64 + c], va);
            }
            size_t o = ((size_t)b * Nn + i0 + r) * 64 + c;
            Uh[o] = (_Float16)ua;
            Vh[o] = (_Float16)va;
        }
    }
}

// ---------------- edge MLP: full region per wave, LDS-staged weights, RELAXED VGPR BUDGET ----------------
// __launch_bounds__(256, 4): allow <=128 VGPR so invariants + part[] stay in registers and
// the 32 U-loads can be software-pipelined across rows (R12's VGPR=52 forced remat+serial chain).
__global__ __launch_bounds__(256, 4) void edge_kernel(
    const _Float16* __restrict__ Uh, const _Float16* __restrict__ Vh,
    const float* __restrict__ E2, const float* __restrict__ e2,
    const float* __restrict__ E3, const float* __restrict__ e3,
    float* __restrict__ adj) {
    __shared__ _Float16 sE2T[2][2][4][16][8];   // 4 KB: [ct][ks][g][x][jj] pre-transposed E2
    __shared__ float sBias[65];                 // e2[32] | E3[32] | e3
    __shared__ float sW[4][16][20];             // 5 KB: mirror tile staging
    int t = threadIdx.x, lane = t & 63, w = t >> 6;
    int x = lane & 15, g = lane >> 4;

    // ---- block-level staging (one coalesced pass) ----
    {
        int ct = t >> 7, ks = (t >> 6) & 1, gg = (t >> 4) & 3, xx = t & 15;
#pragma unroll
        for (int jj = 0; jj < 8; ++jj)
            sE2T[ct][ks][gg][xx][jj] = (_Float16)E2[(32 * ks + 8 * gg + jj) * Hh + 16 * ct + xx];
    }
    if (t < 32) sBias[t] = e2[t];
    else if (t < 64) sBias[t] = E3[t - 32];
    else if (t == 64) sBias[64] = e3[0];
    __syncthreads();

    // per-wave invariants from LDS
    f16x8 ea[2][2];
#pragma unroll
    for (int ct = 0; ct < 2; ++ct)
#pragma unroll
        for (int ks = 0; ks < 2; ++ks)
            ea[ct][ks] = *reinterpret_cast<const f16x8*>(&sE2T[ct][ks][g][x][0]);

    float e2a[4], e2b[4], E3a[4], E3b[4];
#pragma unroll
    for (int rg = 0; rg < 4; ++rg) {
        e2a[rg] = sBias[4 * g + rg];      E3a[rg] = sBias[32 + 4 * g + rg];
        e2b[rg] = sBias[16 + 4 * g + rg]; E3b[rg] = sBias[48 + 4 * g + rg];
    }
    float e3s = sBias[64];

    // ---- region index: one full region per wave ----
    int tr = blockIdx.x * 4 + w;
    int b = 0;
    if (tr >= TREG) { b = 1; tr -= TREG; }
    float ft = (float)tr;
    int ib = (int)((193.0f - sqrtf(193.0f * 193.0f - 8.0f * ft)) * 0.5f);
    ib = ib < 0 ? 0 : (ib > Nb - 1 ? Nb - 1 : ib);
    while (ib < Nb - 1 && (ib + 1) * Nb - ((ib + 1) * ib) / 2 <= tr) ++ib;
    while (ib > 0 && ib * Nb - (ib * (ib - 1)) / 2 > tr) --ib;
    int jb = ib + (tr - (ib * Nb - (ib * (ib - 1)) / 2));
    int i0 = ib * 16, j0 = jb * 16;
    bool diag = (ib == jb);

    const f16x8* Vrow = reinterpret_cast<const f16x8*>(Vh + ((size_t)b * Nn + j0 + x) * 64);
    f16x8 vf0 = Vrow[g];
    f16x8 vf1 = Vrow[4 + g];

    const f16x8* Ubase = reinterpret_cast<const f16x8*>(Uh + ((size_t)b * Nn + i0) * 64);

    if (diag && lane < 16) sW[w][lane][lane] = 0.f;

    const f16x8 fz = {0, 0, 0, 0, 0, 0, 0, 0};

    // phase 1: per-row MFMA + lane-local partial (pure dataflow, fully unrolled)
    float part[16];
#pragma unroll
    for (int r = 0; r < 16; ++r) {
        f16x8 u0 = Ubase[r * 8 + g];
        f16x8 u1 = Ubase[r * 8 + 4 + g];
        f16x8 af0 = __builtin_elementwise_max(u0 + vf0, fz);
        f16x8 af1 = __builtin_elementwise_max(u1 + vf1, fz);

        f32x4 acc0 = {e2a[0], e2a[1], e2a[2], e2a[3]};
        f32x4 acc1 = {e2b[0], e2b[1], e2b[2], e2b[3]};
        acc0 = __builtin_amdgcn_mfma_f32_16x16x32_f16(ea[0][0], af0, acc0, 0, 0, 0);
        acc0 = __builtin_amdgcn_mfma_f32_16x16x32_f16(ea[0][1], af1, acc0, 0, 0, 0);
        acc1 = __builtin_amdgcn_mfma_f32_16x16x32_f16(ea[1][0], af0, acc1, 0, 0, 0);
        acc1 = __builtin_amdgcn_mfma_f32_16x16x32_f16(ea[1][1], af1, acc1, 0, 0, 0);

        float p = 0.f;
#pragma unroll
        for (int rg = 0; rg < 4; ++rg) {
            p = fmaf(fmaxf(acc0[rg], 0.f), E3a[rg], p);
            p = fmaf(fmaxf(acc1[rg], 0.f), E3b[rg], p);
        }
        part[r] = p;
    }

    // phase 2: batched cross-lane reduce (independent chains)
#pragma unroll
    for (int r = 0; r < 16; ++r) part[r] += permswap32(part[r]);
#pragma unroll
    for (int r = 0; r < 16; ++r) part[r] += permswap16(part[r]);

    // phase 3: batched sigmoid
    float wv[16];
#pragma unroll
    for (int r = 0; r < 16; ++r) {
        float logit = part[r] + e3s;
        wv[r] = __builtin_amdgcn_rcpf(1.f + __expf(-logit));
    }

    // phase 4: stores (lanes 0-15 hold valid sums)
    if (g == 0) {
#pragma unroll
        for (int r = 0; r < 16; ++r) {
            if (!diag) {
                adj[((size_t)b * Nn + i0 + r) * Nn + j0 + x] = wv[r];
                sW[w][x][r] = wv[r];
            } else if (x > r) {
                sW[w][r][x] = wv[r];
                sW[w][x][r] = wv[r];
            }
        }
    }

    // phase 5: region-level coalesced store of the mirrored tile (same-wave LDS, no barrier)
    {
        int rr = lane >> 2, m4 = (lane & 3) * 4;
        float4 wv4 = *reinterpret_cast<const float4*>(&sW[w][rr][m4]);
        if (!diag)
            *reinterpret_cast<float4*>(&adj[((size_t)b * Nn + j0 + rr) * Nn + i0 + m4]) = wv4;
        else
            *reinterpret_cast<float4*>(&adj[((size_t)b * Nn + i0 + rr) * Nn + i0 + m4]) = wv4;
    }
}

extern "C" void kernel_launch(void* const* d_in, const int* in_sizes, int n_in,
                              void* d_out, int out_size, void* d_ws, size_t ws_size,
                              hipStream_t stream) {
    const float* A   = (const float*)d_in[0];
    const float* emb = (const float*)d_in[1];
    const float* W1  = (const float*)d_in[2];  const float* b1  = (const float*)d_in[3];
    const float* W2  = (const float*)d_in[4];  const float* b2  = (const float*)d_in[5];
    const float* W3  = (const float*)d_in[6];  const float* b3  = (const float*)d_in[7];
    const float* Wmu = (const float*)d_in[8];  const float* bmu = (const float*)d_in[9];
    const float* Wlv = (const float*)d_in[10]; const float* blv = (const float*)d_in[11];
    const float* E1  = (const float*)d_in[12]; const float* e1  = (const float*)d_in[13];
    const float* E2  = (const float*)d_in[14]; const float* e2  = (const float*)d_in[15];
    const float* E3  = (const float*)d_in[16]; const float* e3  = (const float*)d_in[17];

    float* out = (float*)d_out;
    float* ws  = (float*)d_ws;
    float* dinv = ws;
    float* hA   = ws + 3072;
    float* hB   = ws + 101376;
    __hip_bfloat16* xsTa = (__hip_bfloat16*)(ws + 199680);
    __hip_bfloat16* xsTb = (__hip_bfloat16*)(ws + 248832);
    _Float16* Uh = (_Float16*)(ws + 297984);
    _Float16* Vh = (_Float16*)(ws + 396288);
    __hip_bfloat16* Abf = (__hip_bfloat16*)out;   // aliases adj region; overwritten by edge later

    float* mu_out = out + (size_t)Bb * Nn * Nn;
    float* lv_out = mu_out + (size_t)Bb * Nn * Ll;

    prep_kernel<<<(Bb * Nn + 3) / 4, 256, 0, stream>>>(A, Abf, dinv, emb, W1, xsTa);

    prop_kernel<<<Bb * Nb, 256, 0, stream>>>(Abf, xsTa, dinv, b1, nullptr, hA, 0,
                                             W2, xsTb, 0,
                                             nullptr, nullptr, nullptr, nullptr,
                                             nullptr, nullptr, nullptr, nullptr,
                                             nullptr, nullptr);
    prop_kernel<<<Bb * Nb, 256, 0, stream>>>(Abf, xsTb, dinv, b2, hA, hB, 1,
                                             W3, xsTa, 0,
                                             nullptr, nullptr, nullptr, nullptr,
                                             nullptr, nullptr, nullptr, nullptr,
                                             nullptr, nullptr);
    prop_kernel<<<Bb * Nb, 256, 0, stream>>>(Abf, xsTa, dinv, b3, hB, hA, 1,
                                             nullptr, nullptr, 1,
                                             Wmu, bmu, Wlv, blv, E1, e1,
                                             mu_out, lv_out, Uh, Vh);

    // 9312 regions, one per wave -> 2328 blocks
    edge_kernel<<<(2 * TREG) / 4, 256, 0, stream>>>(Uh, Vh, E2, e2, E3, e3, out);
}